// Round 1
// 131.544 us; speedup vs baseline: 1.0690x; 1.0690x over previous
//
#include <hip/hip_runtime.h>

#define LEAKY(t) ((t) > 0.0f ? (t) : 0.01f*(t))

typedef __attribute__((ext_vector_type(8))) short short8;
typedef __attribute__((ext_vector_type(4))) float floatx4;

// fp32 -> bf16 (round to nearest even), bits in a short
static __device__ __forceinline__ short f2bf(float f) {
  unsigned u = __float_as_uint(f);
  u += 0x7FFFu + ((u >> 16) & 1u);
  return (short)(u >> 16);
}

// ---------------------------------------------------------------------------
// Workspace (float index):
//   dpart @ 0       12*64*384 = 294912   descriptor partials (plain stores,
//                                        one slot per (par,chunk); no atomics,
//                                        no pre-zero needed)
//   pre   @ 294912  192                  fit4 pre-mean output
//   g_WT  @ 295104  33792 shorts         MFMA B-fragment tables (lane-indexed)
// No device fences anywhere: cross-kernel visibility via stream ordering.
// ---------------------------------------------------------------------------

// ---------------------------------------------------------------------------
// Prep: build MFMA B-fragment tables only (d-zero removed: embed now writes
// every dpart entry with plain stores).
// B-frag layout for 16x16x32: lane=(col=o_local, quad), element j -> k=quad*8+j.
// Layer-1 trick: k<3 -> We1[k][o], k==3 -> be1[o] (A supplies 1.0 at k=3).
// ---------------------------------------------------------------------------
__global__ __launch_bounds__(256) void prep_kernel(
    const float* __restrict__ We1, const float* __restrict__ be1,
    const float* __restrict__ We2, const float* __restrict__ We3,
    short* __restrict__ g_WT)
{
  const int gt = blockIdx.x * 256 + threadIdx.x;
  const int GS = gridDim.x * 256;
  for (int it = gt; it < 4224; it += GS) {
    short8 v;
    if (it < 384) {
      const int p = it >> 7, r = it & 127, ot = (r >> 6) & 1, ln = r & 63;
      const int col = ln & 15, quad = ln >> 4, o = ot * 16 + col;
      #pragma unroll
      for (int j = 0; j < 8; ++j) {
        const int k = quad * 8 + j;
        float f = 0.0f;
        if (k < 3) f = We1[p * 96 + k * 32 + o];
        else if (k == 3) f = be1[p * 32 + o];
        v[j] = f2bf(f);
      }
    } else if (it < 1152) {
      const int t = it - 384;
      const int p = t >> 8, r = t & 255, ot = r >> 6, ln = r & 63;
      const int col = ln & 15, quad = ln >> 4, o = ot * 16 + col;
      #pragma unroll
      for (int j = 0; j < 8; ++j) {
        const int k = quad * 8 + j;
        v[j] = f2bf(We2[p * 2048 + k * 64 + o]);
      }
    } else {
      const int t = it - 1152;
      const int p = t >> 10, r = t & 1023, ot = r >> 7, rr = r & 127;
      const int ks = rr >> 6, ln = rr & 63;
      const int col = ln & 15, quad = ln >> 4, o = ot * 16 + col;
      #pragma unroll
      for (int j = 0; j < 8; ++j) {
        const int k = ks * 32 + quad * 8 + j;
        v[j] = f2bf(We3[p * 8192 + k * 128 + o]);
      }
    }
    *(short8*)(g_WT + it * 8) = v;
  }
}

// ---------------------------------------------------------------------------
// Embedding + descriptor, all-MFMA, weights in registers (no LDS staging).
// grid (64 n, 2 par, 6 chunk), 256 thr; chunk = 144 pairs = 9 m-tiles.
// LDS only holds activations: 36.9 KB -> 4 blocks/CU.
// keep = (dist<=25) && (m!=n); pair-type p depends only on (n%2, j%2).
// Descriptor written as PLAIN STORES into dpart[par*6+chunk][n][384]
// (each (n,o,c) is owned by exactly one wave of exactly one block).
// ---------------------------------------------------------------------------
__global__ __launch_bounds__(256, 4) void embed_kernel(
    const float* __restrict__ x, const float* __restrict__ lattice,
    const short* __restrict__ g_WT,
    const float* __restrict__ be2, const float* __restrict__ be3,
    const int* __restrict__ types, float* __restrict__ dpart)
{
  __shared__ __align__(16) float rel4[144 * 4];   // {rel0,rel1,rel2,1.0}
  __shared__ __align__(16) float rk4[144 * 4];    // rel*keep
  __shared__ __align__(16) short h1s[144 * 40];   // bf16, stride 40
  __shared__ __align__(16) short h2s[144 * 72];   // bf16, stride 72

  const int n = blockIdx.x, par = blockIdx.y, chunk = blockIdx.z;
  const int tid = threadIdx.x;
  const int lane = tid & 63, w = tid >> 6;
  const int col = lane & 15, quad = lane >> 4;

  const int tn = types[n];
  const int tj = types[par];
  const int lo = tn < tj ? tn : tj;
  const int hi = tn < tj ? tj : tn;
  const int p  = lo * 2 - (lo * (lo - 1)) / 2 + (hi - lo);

  // ---- B-fragments straight from global into registers (L2-hot) ----
  const short8* WT8 = (const short8*)g_WT;
  const short8 w1b0 = WT8[(p * 2 + 0) * 64 + lane];
  const short8 w1b1 = WT8[(p * 2 + 1) * 64 + lane];
  short8 w2b[4];
  #pragma unroll
  for (int ot = 0; ot < 4; ++ot) w2b[ot] = WT8[384 + (p * 4 + ot) * 64 + lane];
  short8 w3b[2][2];
  #pragma unroll
  for (int nt = 0; nt < 2; ++nt)
    #pragma unroll
    for (int ks = 0; ks < 2; ++ks)
      w3b[nt][ks] = WT8[1152 + ((p * 8 + 2 * w + nt) * 2 + ks) * 64 + lane];
  float bias2[4];
  #pragma unroll
  for (int ot = 0; ot < 4; ++ot) bias2[ot] = be2[p * 64 + ot * 16 + col];
  float bias3[2];
  #pragma unroll
  for (int nt = 0; nt < 2; ++nt) bias3[nt] = be3[p * 128 + w * 32 + nt * 16 + col];

  // ---- rel / keep, one thread per pair ----
  if (tid < 144) {
    const int q  = chunk * 144 + tid;
    const int c  = q >> 5;
    const int jj = q & 31;
    const int j  = 2 * jj + par;
    const float f0 = (float)(c / 9);
    const float f1 = (float)((c / 3) % 3);
    const float f2c = (float)(c % 3);
    const float rel0 = x[j*3+0] - x[n*3+0] + f0*lattice[0] + f1*lattice[3] + f2c*lattice[6];
    const float rel1 = x[j*3+1] - x[n*3+1] + f0*lattice[1] + f1*lattice[4] + f2c*lattice[7];
    const float rel2 = x[j*3+2] - x[n*3+2] + f0*lattice[2] + f1*lattice[5] + f2c*lattice[8];
    const float dist2 = rel0*rel0 + rel1*rel1 + rel2*rel2;
    const int m = c * 64 + j;
    const bool keep = (dist2 <= 625.0f) && (m != n);
    const float kf = keep ? 1.0f : 0.0f;
    rel4[tid*4+0] = rel0; rel4[tid*4+1] = rel1;
    rel4[tid*4+2] = rel2; rel4[tid*4+3] = 1.0f;
    rk4[tid*4+0] = rel0*kf; rk4[tid*4+1] = rel1*kf;
    rk4[tid*4+2] = rel2*kf; rk4[tid*4+3] = 0.0f;
  }
  __syncthreads();

  // ---- layer 1 (3->32) via MFMA, m-tiles split across waves ----
  for (int mt = w; mt < 9; mt += 4) {
    const float4 r4 = *(const float4*)&rel4[(mt*16 + col) * 4];
    short8 a = {0, 0, 0, 0, 0, 0, 0, 0};
    if (quad == 0) {
      a[0] = f2bf(r4.x); a[1] = f2bf(r4.y); a[2] = f2bf(r4.z);
      a[3] = (short)0x3F80;   // 1.0 -> picks up bias row k=3
    }
    const floatx4 z = {0.f, 0.f, 0.f, 0.f};
    const floatx4 c0 = __builtin_amdgcn_mfma_f32_16x16x32_bf16(a, w1b0, z, 0, 0, 0);
    const floatx4 c1 = __builtin_amdgcn_mfma_f32_16x16x32_bf16(a, w1b1, z, 0, 0, 0);
    #pragma unroll
    for (int r = 0; r < 4; ++r) {
      const int pair = mt*16 + quad*4 + r;
      h1s[pair*40 +      col] = f2bf(LEAKY(c0[r]));
      h1s[pair*40 + 16 + col] = f2bf(LEAKY(c1[r]));
    }
  }
  __syncthreads();

  // ---- layer 2 (32->64) via MFMA, m-tiles split across waves ----
  for (int mt = w; mt < 9; mt += 4) {
    const short8 a = *(const short8*)&h1s[(mt*16 + col) * 40 + quad*8];
    #pragma unroll
    for (int ot = 0; ot < 4; ++ot) {
      floatx4 acc = {bias2[ot], bias2[ot], bias2[ot], bias2[ot]};
      acc = __builtin_amdgcn_mfma_f32_16x16x32_bf16(a, w2b[ot], acc, 0, 0, 0);
      #pragma unroll
      for (int r = 0; r < 4; ++r) {
        const int pair = mt*16 + quad*4 + r;
        h2s[pair*72 + ot*16 + col] = f2bf(LEAKY(acc[r]));
      }
    }
  }
  __syncthreads();

  // ---- layer 3 (64->128) MFMA, wave w owns o-tiles {2w,2w+1}; fused desc ----
  float vacc[2][3] = {{0,0,0},{0,0,0}};
  for (int mt = 0; mt < 9; ++mt) {
    const short8 a0 = *(const short8*)&h2s[(mt*16 + col) * 72 +      quad*8];
    const short8 a1 = *(const short8*)&h2s[(mt*16 + col) * 72 + 32 + quad*8];
    float4 rks[4];
    #pragma unroll
    for (int r = 0; r < 4; ++r)
      rks[r] = *(const float4*)&rk4[(mt*16 + quad*4 + r) * 4];
    #pragma unroll
    for (int nt = 0; nt < 2; ++nt) {
      floatx4 acc = {bias3[nt], bias3[nt], bias3[nt], bias3[nt]};
      acc = __builtin_amdgcn_mfma_f32_16x16x32_bf16(a0, w3b[nt][0], acc, 0, 0, 0);
      acc = __builtin_amdgcn_mfma_f32_16x16x32_bf16(a1, w3b[nt][1], acc, 0, 0, 0);
      #pragma unroll
      for (int r = 0; r < 4; ++r) {
        const float h3 = LEAKY(acc[r]);
        vacc[nt][0] += h3 * rks[r].x;
        vacc[nt][1] += h3 * rks[r].y;
        vacc[nt][2] += h3 * rks[r].z;
      }
    }
  }
  #pragma unroll
  for (int nt = 0; nt < 2; ++nt)
    #pragma unroll
    for (int c = 0; c < 3; ++c) {
      float v = vacc[nt][c];
      v += __shfl_xor(v, 16, 64);
      v += __shfl_xor(v, 32, 64);
      vacc[nt][c] = v;
    }
  if (lane < 32) {
    const int nts = lane >> 4, colw = lane & 15;
    const int o = w*32 + nts*16 + colw;
    const int slot = par * 6 + chunk;
    float* dst = dpart + ((size_t)(slot * 64 + n)) * 384 + o * 3;
    #pragma unroll
    for (int c = 0; c < 3; ++c)
      dst[c] = nts ? vacc[1][c] : vacc[0][c];
  }
}

// ---------------------------------------------------------------------------
// Fused fit: d(384) -> 256 -> 256 -> 128 -> 3 in ONE kernel.
// grid 64 (one block per atom n), 512 threads (8 waves).
// Layers chained through LDS; per-layer decomposition keeps W loads fully
// coalesced (consecutive lanes cover one contiguous weight row):
//   L1: 64 o4-groups x 8 i-slices(48)   -> wave reads 1KB contiguous row
//   L2: 64 o4-groups x 8 i-slices(32)
//   L3: 32 o4-groups x 16 i-slices(16)  -> half-wave reads 512B row
//   L4: 128 threads, shfl reduce
// Weight traffic 788 KB/block, L3-resident -> ~3-5 us for the whole chain.
// ---------------------------------------------------------------------------
__global__ __launch_bounds__(512) void fit_kernel(
    const float* __restrict__ dpart,
    const float* __restrict__ W1, const float* __restrict__ b1,
    const float* __restrict__ W2, const float* __restrict__ b2,
    const float* __restrict__ W3, const float* __restrict__ b3,
    const float* __restrict__ W4, const float* __restrict__ b4,
    float* __restrict__ pre)
{
  __shared__ __align__(16) float a0[384];
  __shared__ __align__(16) float a1[256];
  __shared__ __align__(16) float a2[256];
  __shared__ __align__(16) float a3[128];
  __shared__ __align__(16) floatx4 red[512];
  const int n = blockIdx.x, tid = threadIdx.x;

  // ---- gather descriptor: sum the 12 (par,chunk) partials ----
  for (int i = tid; i < 384; i += 512) {
    float s = 0.f;
    #pragma unroll
    for (int sl = 0; sl < 12; ++sl)
      s += dpart[((size_t)(sl * 64 + n)) * 384 + i];
    a0[i] = s;
  }
  __syncthreads();

  // ---- L1: 384 -> 256 ----
  {
    const int g = tid & 63, s = tid >> 6;
    const float* Wp = W1 + (size_t)n * 98304 + 4 * g;
    floatx4 acc = {0.f, 0.f, 0.f, 0.f};
    #pragma unroll 16
    for (int k = 0; k < 48; ++k) {
      const int i = s * 48 + k;
      acc += a0[i] * *(const floatx4*)(Wp + (size_t)i * 256);
    }
    red[tid] = acc;
    __syncthreads();
    if (tid < 64) {
      floatx4 v = red[tid];
      #pragma unroll
      for (int s2 = 1; s2 < 8; ++s2) v += red[s2 * 64 + tid];
      const float4 bb = *(const float4*)&b1[n * 256 + 4 * tid];
      a1[4*tid+0] = LEAKY(v[0] + bb.x);
      a1[4*tid+1] = LEAKY(v[1] + bb.y);
      a1[4*tid+2] = LEAKY(v[2] + bb.z);
      a1[4*tid+3] = LEAKY(v[3] + bb.w);
    }
    __syncthreads();
  }

  // ---- L2: 256 -> 256 ----
  {
    const int g = tid & 63, s = tid >> 6;
    const float* Wp = W2 + (size_t)n * 65536 + 4 * g;
    floatx4 acc = {0.f, 0.f, 0.f, 0.f};
    #pragma unroll 16
    for (int k = 0; k < 32; ++k) {
      const int i = s * 32 + k;
      acc += a1[i] * *(const floatx4*)(Wp + (size_t)i * 256);
    }
    red[tid] = acc;
    __syncthreads();
    if (tid < 64) {
      floatx4 v = red[tid];
      #pragma unroll
      for (int s2 = 1; s2 < 8; ++s2) v += red[s2 * 64 + tid];
      const float4 bb = *(const float4*)&b2[n * 256 + 4 * tid];
      a2[4*tid+0] = LEAKY(v[0] + bb.x);
      a2[4*tid+1] = LEAKY(v[1] + bb.y);
      a2[4*tid+2] = LEAKY(v[2] + bb.z);
      a2[4*tid+3] = LEAKY(v[3] + bb.w);
    }
    __syncthreads();
  }

  // ---- L3: 256 -> 128 ----
  {
    const int g = tid & 31, s = tid >> 5;
    const float* Wp = W3 + (size_t)n * 32768 + 4 * g;
    floatx4 acc = {0.f, 0.f, 0.f, 0.f};
    #pragma unroll
    for (int k = 0; k < 16; ++k) {
      const int i = s * 16 + k;
      acc += a2[i] * *(const floatx4*)(Wp + (size_t)i * 128);
    }
    red[tid] = acc;
    __syncthreads();
    if (tid < 32) {
      floatx4 v = red[tid];
      #pragma unroll
      for (int s2 = 1; s2 < 16; ++s2) v += red[s2 * 32 + tid];
      const float4 bb = *(const float4*)&b3[n * 128 + 4 * tid];
      a3[4*tid+0] = LEAKY(v[0] + bb.x);
      a3[4*tid+1] = LEAKY(v[1] + bb.y);
      a3[4*tid+2] = LEAKY(v[2] + bb.z);
      a3[4*tid+3] = LEAKY(v[3] + bb.w);
    }
    __syncthreads();
  }

  // ---- L4: 128 -> 3 (no activation) ----
  {
    float* redf = (float*)red;
    if (tid < 128) {
      const float hv = a3[tid];
      const float* W4n = W4 + (size_t)n * 384;
      float p0 = hv * W4n[tid*3 + 0];
      float p1 = hv * W4n[tid*3 + 1];
      float p2 = hv * W4n[tid*3 + 2];
      #pragma unroll
      for (int off = 32; off >= 1; off >>= 1) {
        p0 += __shfl_down(p0, off, 64);
        p1 += __shfl_down(p1, off, 64);
        p2 += __shfl_down(p2, off, 64);
      }
      if ((tid & 63) == 0) {
        const int wv = tid >> 6;
        redf[wv*3 + 0] = p0; redf[wv*3 + 1] = p1; redf[wv*3 + 2] = p2;
      }
    }
    __syncthreads();
    if (tid < 3)
      pre[n*3 + tid] = redf[tid] + redf[3 + tid] + b4[n*3 + tid];
  }
}

// ---------------------------------------------------------------------------
// Mean-subtract over atoms (needs all n): 1 block, 256 thr.
// ---------------------------------------------------------------------------
__global__ __launch_bounds__(256) void mean_kernel(
    const float* __restrict__ pre, float* __restrict__ out)
{
  __shared__ float sp[192];
  __shared__ float meanv[3];
  const int tid = threadIdx.x;
  if (tid < 192) sp[tid] = pre[tid];
  __syncthreads();
  if (tid < 3) {
    float s = 0.f;
    #pragma unroll
    for (int nn = 0; nn < 64; ++nn) s += sp[nn*3 + tid];
    meanv[tid] = s * (1.0f / 64.0f);
  }
  __syncthreads();
  if (tid < 192) out[tid] = sp[tid] - meanv[tid % 3];
}

// ---------------------------------------------------------------------------
extern "C" void kernel_launch(void* const* d_in, const int* in_sizes, int n_in,
                              void* d_out, int out_size, void* d_ws, size_t ws_size,
                              hipStream_t stream) {
  const float* x       = (const float*)d_in[0];
  const float* lattice = (const float*)d_in[1];
  const float* We1 = (const float*)d_in[2];
  const float* be1 = (const float*)d_in[3];
  const float* We2 = (const float*)d_in[4];
  const float* be2 = (const float*)d_in[5];
  const float* We3 = (const float*)d_in[6];
  const float* be3 = (const float*)d_in[7];
  const float* Wl1 = (const float*)d_in[8];
  const float* bl1 = (const float*)d_in[9];
  const float* Wl2 = (const float*)d_in[10];
  const float* bl2 = (const float*)d_in[11];
  const float* Wl3 = (const float*)d_in[12];
  const float* bl3 = (const float*)d_in[13];
  const float* Wl4 = (const float*)d_in[14];
  const float* bl4 = (const float*)d_in[15];
  const int*   types = (const int*)d_in[16];

  float* wsf   = (float*)d_ws;
  float* dpart = wsf;                      // 294912 floats
  float* pre   = wsf + 294912;             // 192 floats
  short* g_WT  = (short*)(wsf + 295104);   // 33792 shorts (16B aligned)

  prep_kernel<<<17, 256, 0, stream>>>(We1, be1, We2, We3, g_WT);
  embed_kernel<<<dim3(64, 2, 6), 256, 0, stream>>>(
      x, lattice, g_WT, be2, be3, types, dpart);
  fit_kernel<<<64, 512, 0, stream>>>(
      dpart, Wl1, bl1, Wl2, bl2, Wl3, bl3, Wl4, bl4, pre);
  mean_kernel<<<1, 256, 0, stream>>>(pre, (float*)d_out);
}